// Round 1
// baseline (6002.148 us; speedup 1.0000x reference)
//
#include <hip/hip_runtime.h>
#include <float.h>

#define N_PTS   50000
#define M_CENT  2048
#define K_LOC   32
#define C_CH    128

typedef unsigned long long u64;
typedef unsigned int u32;

// ---------------- FPS ----------------
// 16 co-resident blocks (way below 256 CUs -> residency guaranteed), custom
// one-barrier-per-iteration protocol through device-scope atomics.
#define FPS_NB  16
#define FPS_NT  1024
#define FPS_TOT (FPS_NB*FPS_NT)
#define FPS_PPT 4   // 16*1024*4 = 65536 >= 50000

__global__ void zero_ws_kernel(u64* winner, int* ctr) {
  int t = blockIdx.x * blockDim.x + threadIdx.x;
  if (t < M_CENT) { winner[t] = 0ull; ctr[t] = 0; }
}

__global__ __launch_bounds__(FPS_NT, 4) void fps_kernel(
    const float* __restrict__ pos,
    u64* __restrict__ winner,   // [M_CENT], zeroed
    int* __restrict__ ctr,      // [M_CENT], zeroed
    float* __restrict__ cent_out)  // d_out[0 .. 3*M_CENT)
{
  const int tid = threadIdx.x;
  const int gt  = blockIdx.x * FPS_NT + tid;

  float px[FPS_PPT], py[FPS_PPT], pz[FPS_PPT], dist[FPS_PPT];
#pragma unroll
  for (int j = 0; j < FPS_PPT; j++) {
    int n = gt + j * FPS_TOT;
    if (n < N_PTS) {
      px[j] = pos[3*n+0]; py[j] = pos[3*n+1]; pz[j] = pos[3*n+2];
      dist[j] = FLT_MAX;                 // matches finfo(f32).max init
    } else {
      px[j] = 0.f; py[j] = 0.f; pz[j] = 0.f; dist[j] = -1.f;  // never contributes
    }
  }

  __shared__ u64 wred[FPS_NT/64];
  __shared__ int s_c;

  int c = 0;  // deterministic start at index 0 (matches reference)
  for (int i = 0; i < M_CENT; i++) {
    float cx = pos[3*c+0], cy = pos[3*c+1], cz = pos[3*c+2];
    if (blockIdx.x == 0 && tid == 0) {
      cent_out[3*i+0] = cx; cent_out[3*i+1] = cy; cent_out[3*i+2] = cz;
    }
    u64 best = 0ull;
#pragma unroll
    for (int j = 0; j < FPS_PPT; j++) {
      int n = gt + j * FPS_TOT;
      if (n < N_PTS) {
        // exact reference arithmetic: no FMA contraction, ((dx^2+dy^2)+dz^2)
        float dx = __fsub_rn(px[j], cx);
        float dy = __fsub_rn(py[j], cy);
        float dz = __fsub_rn(pz[j], cz);
        float d2 = __fadd_rn(__fadd_rn(__fmul_rn(dx,dx), __fmul_rn(dy,dy)),
                             __fmul_rn(dz,dz));
        float d  = fminf(dist[j], d2);
        dist[j] = d;
        // pack: larger dist wins; tie -> smaller index (via complement)
        u64 pk = ((u64)__float_as_uint(d) << 32) | (u64)(0xFFFFFFFFu - (u32)n);
        if (pk > best) best = pk;
      }
    }
#pragma unroll
    for (int off = 32; off >= 1; off >>= 1) {
      u64 o = __shfl_down(best, off, 64);
      if (o > best) best = o;
    }
    if ((tid & 63) == 0) wred[tid >> 6] = best;
    __syncthreads();
    if (i < M_CENT - 1) {
      if (tid < 64) {
        best = (tid < FPS_NT/64) ? wred[tid] : 0ull;
#pragma unroll
        for (int off = 8; off >= 1; off >>= 1) {
          u64 o = __shfl_down(best, off, 64);
          if (o > best) best = o;
        }
        if (tid == 0) {
          __hip_atomic_fetch_max(&winner[i], best, __ATOMIC_RELAXED, __HIP_MEMORY_SCOPE_AGENT);
          __hip_atomic_fetch_add(&ctr[i], 1, __ATOMIC_ACQ_REL, __HIP_MEMORY_SCOPE_AGENT);
          while (__hip_atomic_load(&ctr[i], __ATOMIC_ACQUIRE, __HIP_MEMORY_SCOPE_AGENT) < FPS_NB) {
            __builtin_amdgcn_s_sleep(1);
          }
          u64 w = __hip_atomic_load(&winner[i], __ATOMIC_ACQUIRE, __HIP_MEMORY_SCOPE_AGENT);
          s_c = (int)(0xFFFFFFFFu - (u32)(w & 0xFFFFFFFFull));
        }
      }
      __syncthreads();
      c = s_c;
    }
  }
}

// ---------------- Ball query ----------------
#define BQ_NT  256
#define BQ_CAP 2048   // expected ~209 candidates/centroid; huge safety margin

__global__ __launch_bounds__(BQ_NT) void ballq_kernel(
    const float* __restrict__ pos,
    const float* __restrict__ cent,   // centroid coords (from d_out)
    int* __restrict__ nbr,            // [M_CENT*K_LOC]
    int* __restrict__ nsel)           // [M_CENT]
{
  __shared__ float s_d2[BQ_CAP];
  __shared__ int   s_idx[BQ_CAP];
  __shared__ int   s_count;
  __shared__ u64   s_red[BQ_NT/64];
  __shared__ u64   s_win;

  const int m = blockIdx.x, tid = threadIdx.x;
  if (tid == 0) s_count = 0;
  __syncthreads();
  const float cx = cent[3*m+0], cy = cent[3*m+1], cz = cent[3*m+2];

  for (int n = tid; n < N_PTS; n += BQ_NT) {
    float dx = __fsub_rn(cx, pos[3*n+0]);
    float dy = __fsub_rn(cy, pos[3*n+1]);
    float dz = __fsub_rn(cz, pos[3*n+2]);
    float d2 = __fadd_rn(__fadd_rn(__fmul_rn(dx,dx), __fmul_rn(dy,dy)),
                         __fmul_rn(dz,dz));
    if (d2 <= 0.01f) {   // same f32 value as (float)(0.1*0.1)
      int p = atomicAdd(&s_count, 1);
      if (p < BQ_CAP) { s_d2[p] = d2; s_idx[p] = n; }
    }
  }
  __syncthreads();
  int cnt = s_count; if (cnt > BQ_CAP) cnt = BQ_CAP;
  int ns = cnt < K_LOC ? cnt : K_LOC;

  // exact top_k semantics: k smallest d2, ties -> smaller index
  for (int sel = 0; sel < ns; sel++) {
    u64 best = ~0ull;
    for (int p = tid; p < cnt; p += BQ_NT) {
      u64 pk = ((u64)__float_as_uint(s_d2[p]) << 32) | (u64)(u32)s_idx[p];
      if (pk < best) best = pk;
    }
#pragma unroll
    for (int off = 32; off >= 1; off >>= 1) {
      u64 o = __shfl_down(best, off, 64);
      if (o < best) best = o;
    }
    if ((tid & 63) == 0) s_red[tid >> 6] = best;
    __syncthreads();
    if (tid < 64) {
      best = (tid < BQ_NT/64) ? s_red[tid] : ~0ull;
#pragma unroll
      for (int off = 2; off >= 1; off >>= 1) {
        u64 o = __shfl_down(best, off, 64);
        if (o < best) best = o;
      }
      if (tid == 0) s_win = best;
    }
    __syncthreads();
    int widx = (int)(u32)(s_win & 0xFFFFFFFFull);
    if (tid == 0) nbr[m*K_LOC + sel] = widx;
    for (int p = tid; p < cnt; p += BQ_NT) {
      if (s_idx[p] == widx) s_d2[p] = FLT_MAX;   // remove winner
    }
    __syncthreads();
  }
  if (tid == 0) nsel[m] = ns;
}

// ---------------- Gather + max-pool + channel mix ----------------
// Max over the valid selected set == reference (fallback idx is the nearest
// valid neighbor, already a member of the set).
__global__ __launch_bounds__(C_CH) void pool_mix_kernel(
    const float* __restrict__ fs,   // (N,128,1)
    const float* __restrict__ fv,   // (N,128,3)
    const float* __restrict__ Ws,
    const float* __restrict__ Wv,
    const float* __restrict__ bs,
    const float* __restrict__ bv,
    const int* __restrict__ nbr,
    const int* __restrict__ nsel,
    float* __restrict__ out_s,      // (M,128,1)
    float* __restrict__ out_v)      // (M,128,3)
{
  __shared__ float ps[C_CH];
  __shared__ float pv[C_CH*3];
  const int m = blockIdx.x, o = threadIdx.x;
  const int ns = nsel[m];
  float mS = -FLT_MAX, m0 = -FLT_MAX, m1 = -FLT_MAX, m2 = -FLT_MAX;
  for (int j = 0; j < ns; j++) {
    int n = nbr[m*K_LOC + j];
    mS = fmaxf(mS, fs[(size_t)n*C_CH + o]);
    const float* r = fv + (size_t)n*(C_CH*3) + 3*o;
    m0 = fmaxf(m0, r[0]); m1 = fmaxf(m1, r[1]); m2 = fmaxf(m2, r[2]);
  }
  ps[o] = mS; pv[3*o+0] = m0; pv[3*o+1] = m1; pv[3*o+2] = m2;
  __syncthreads();
  float aS = bs[o];
  float a0 = bv[o], a1 = bv[o], a2 = bv[o];
  for (int cc = 0; cc < C_CH; cc++) {
    float w1 = Ws[cc*C_CH + o];
    float w2 = Wv[cc*C_CH + o];
    aS = fmaf(ps[cc], w1, aS);
    a0 = fmaf(pv[3*cc+0], w2, a0);
    a1 = fmaf(pv[3*cc+1], w2, a1);
    a2 = fmaf(pv[3*cc+2], w2, a2);
  }
  out_s[(size_t)m*C_CH + o] = aS;
  float* ov = out_v + (size_t)m*(C_CH*3) + 3*o;
  ov[0] = a0; ov[1] = a1; ov[2] = a2;
}

extern "C" void kernel_launch(void* const* d_in, const int* in_sizes, int n_in,
                              void* d_out, int out_size, void* d_ws, size_t ws_size,
                              hipStream_t stream) {
  (void)in_sizes; (void)n_in; (void)out_size; (void)ws_size;
  const float* pos = (const float*)d_in[0];
  const float* fs  = (const float*)d_in[1];
  const float* fv  = (const float*)d_in[2];
  const float* Ws  = (const float*)d_in[3];
  const float* Wv  = (const float*)d_in[4];
  const float* bs  = (const float*)d_in[5];
  const float* bv  = (const float*)d_in[6];

  float* out      = (float*)d_out;
  float* cent_out = out;                               // 2048*3
  float* out_s    = out + 3*M_CENT;                    // 2048*128
  float* out_v    = out + 3*M_CENT + M_CENT*C_CH;      // 2048*128*3

  char* ws = (char*)d_ws;
  u64* winner = (u64*)ws;                                   // 16 KB
  int* ctr    = (int*)(ws + M_CENT*8);                      //  8 KB
  int* nbr    = (int*)(ws + M_CENT*12);                     // 256 KB
  int* nsel   = (int*)(ws + M_CENT*12 + M_CENT*K_LOC*4);    //  8 KB

  zero_ws_kernel<<<(M_CENT+255)/256, 256, 0, stream>>>(winner, ctr);
  fps_kernel<<<FPS_NB, FPS_NT, 0, stream>>>(pos, winner, ctr, cent_out);
  ballq_kernel<<<M_CENT, BQ_NT, 0, stream>>>(pos, cent_out, nbr, nsel);
  pool_mix_kernel<<<M_CENT, C_CH, 0, stream>>>(fs, fv, Ws, Wv, bs, bv,
                                               nbr, nsel, out_s, out_v);
}

// Round 2
// 4816.817 us; speedup vs baseline: 1.2461x; 1.2461x over previous
//
#include <hip/hip_runtime.h>
#include <float.h>

#define N_PTS   50000
#define M_CENT  2048
#define K_LOC   32
#define C_CH    128

typedef unsigned long long u64;
typedef unsigned int u32;

// ---------------- FPS ----------------
// 56 waves (7 blocks x 512 thr), each wave owns a register-resident slice of
// points (14/lane). Per iteration: in-wave butterfly reduce -> one relaxed
// agent-scope store per wave -> every wave polls all 56 slots (lane l polls
// slot l) -> in-wave butterfly max. No __syncthreads, no atomics, no counter:
// the packed value is the message (always nonzero because low32 = ~idx != 0).
#define FPS_NWAVE 56
#define FPS_PPT   14     // 56 waves * 64 lanes * 14 = 50176 >= 50000; wave 55 starts at 49280 < N (no empty wave)

__global__ void init_ws_kernel(u64* __restrict__ slots) {
  int t = blockIdx.x * blockDim.x + threadIdx.x;
  if (t < M_CENT * 64) slots[t] = 0ull;
}

__global__ __launch_bounds__(512) void fps_kernel(
    const float* __restrict__ pos,
    u64* __restrict__ slots,       // [M_CENT*64], zeroed
    float* __restrict__ cent_out)  // d_out[0 .. 3*M_CENT)
{
  const int lane = threadIdx.x & 63;
  const int w    = blockIdx.x * (512 / 64) + (threadIdx.x >> 6);

  float px[FPS_PPT], py[FPS_PPT], pz[FPS_PPT], dist[FPS_PPT];
#pragma unroll
  for (int j = 0; j < FPS_PPT; j++) {
    int n = (w * FPS_PPT + j) * 64 + lane;
    if (n < N_PTS) {
      px[j] = pos[3*n+0]; py[j] = pos[3*n+1]; pz[j] = pos[3*n+2];
      dist[j] = FLT_MAX;                 // matches finfo(f32).max init
    } else {
      px[j] = 0.f; py[j] = 0.f; pz[j] = 0.f; dist[j] = -1.f;  // never contributes
    }
  }

  int c = 0;  // deterministic start at index 0 (matches reference)
  for (int i = 0; i < M_CENT; i++) {
    float cx = pos[3*c+0], cy = pos[3*c+1], cz = pos[3*c+2];
    if (w == 0 && lane == 0) {
      cent_out[3*i+0] = cx; cent_out[3*i+1] = cy; cent_out[3*i+2] = cz;
    }
    u64 best = 0ull;
#pragma unroll
    for (int j = 0; j < FPS_PPT; j++) {
      int n = (w * FPS_PPT + j) * 64 + lane;
      if (n < N_PTS) {
        // exact reference arithmetic: no FMA contraction, ((dx^2+dy^2)+dz^2)
        float dx = __fsub_rn(px[j], cx);
        float dy = __fsub_rn(py[j], cy);
        float dz = __fsub_rn(pz[j], cz);
        float d2 = __fadd_rn(__fadd_rn(__fmul_rn(dx,dx), __fmul_rn(dy,dy)),
                             __fmul_rn(dz,dz));
        float d  = fminf(dist[j], d2);
        dist[j] = d;
        // pack: larger dist wins; tie -> smaller index (via complement)
        u64 pk = ((u64)__float_as_uint(d) << 32) | (u64)(0xFFFFFFFFu - (u32)n);
        if (pk > best) best = pk;
      }
    }
    // in-wave butterfly: all lanes end with the wave max
#pragma unroll
    for (int off = 32; off; off >>= 1) {
      u64 o = __shfl_xor(best, off, 64);
      if (o > best) best = o;
    }
    if (i == M_CENT - 1) break;   // last winner never consumed

    if (lane == 0)
      __hip_atomic_store(&slots[(size_t)i*64 + w], best,
                         __ATOMIC_RELAXED, __HIP_MEMORY_SCOPE_AGENT);

    // poll: lane l waits on slot l (lanes >= NWAVE hold a never-winning sentinel)
    u64 got = (lane < FPS_NWAVE) ? 0ull : 1ull;
    const u64* sl = slots + (size_t)i*64 + lane;
    while (__ballot(got == 0ull)) {
      if (got == 0ull)
        got = __hip_atomic_load(sl, __ATOMIC_RELAXED, __HIP_MEMORY_SCOPE_AGENT);
    }
    u64 win = got;
#pragma unroll
    for (int off = 32; off; off >>= 1) {
      u64 o = __shfl_xor(win, off, 64);
      if (o > win) win = o;
    }
    c = (int)(0xFFFFFFFFu - (u32)win);
  }
}

// ---------------- Ball query ----------------
#define BQ_NT  256
#define BQ_CAP 2048   // expected ~209 candidates/centroid; huge safety margin

__global__ __launch_bounds__(BQ_NT) void ballq_kernel(
    const float* __restrict__ pos,
    const float* __restrict__ cent,   // centroid coords (from d_out)
    int* __restrict__ nbr,            // [M_CENT*K_LOC]
    int* __restrict__ nsel)           // [M_CENT]
{
  __shared__ float s_d2[BQ_CAP];
  __shared__ int   s_idx[BQ_CAP];
  __shared__ int   s_count;
  __shared__ u64   s_red[BQ_NT/64];
  __shared__ u64   s_win;

  const int m = blockIdx.x, tid = threadIdx.x;
  if (tid == 0) s_count = 0;
  __syncthreads();
  const float cx = cent[3*m+0], cy = cent[3*m+1], cz = cent[3*m+2];

  for (int n = tid; n < N_PTS; n += BQ_NT) {
    float dx = __fsub_rn(cx, pos[3*n+0]);
    float dy = __fsub_rn(cy, pos[3*n+1]);
    float dz = __fsub_rn(cz, pos[3*n+2]);
    float d2 = __fadd_rn(__fadd_rn(__fmul_rn(dx,dx), __fmul_rn(dy,dy)),
                         __fmul_rn(dz,dz));
    if (d2 <= 0.01f) {   // same f32 value as (float)(0.1*0.1)
      int p = atomicAdd(&s_count, 1);
      if (p < BQ_CAP) { s_d2[p] = d2; s_idx[p] = n; }
    }
  }
  __syncthreads();
  int cnt = s_count; if (cnt > BQ_CAP) cnt = BQ_CAP;
  int ns = cnt < K_LOC ? cnt : K_LOC;

  // exact top_k semantics: k smallest d2, ties -> smaller index
  for (int sel = 0; sel < ns; sel++) {
    u64 best = ~0ull;
    for (int p = tid; p < cnt; p += BQ_NT) {
      u64 pk = ((u64)__float_as_uint(s_d2[p]) << 32) | (u64)(u32)s_idx[p];
      if (pk < best) best = pk;
    }
#pragma unroll
    for (int off = 32; off >= 1; off >>= 1) {
      u64 o = __shfl_down(best, off, 64);
      if (o < best) best = o;
    }
    if ((tid & 63) == 0) s_red[tid >> 6] = best;
    __syncthreads();
    if (tid < 64) {
      best = (tid < BQ_NT/64) ? s_red[tid] : ~0ull;
#pragma unroll
      for (int off = 2; off >= 1; off >>= 1) {
        u64 o = __shfl_down(best, off, 64);
        if (o < best) best = o;
      }
      if (tid == 0) s_win = best;
    }
    __syncthreads();
    int widx = (int)(u32)(s_win & 0xFFFFFFFFull);
    if (tid == 0) nbr[m*K_LOC + sel] = widx;
    for (int p = tid; p < cnt; p += BQ_NT) {
      if (s_idx[p] == widx) s_d2[p] = FLT_MAX;   // remove winner
    }
    __syncthreads();
  }
  if (tid == 0) nsel[m] = ns;
}

// ---------------- Gather + max-pool + channel mix ----------------
// Max over the valid selected set == reference (fallback idx is the nearest
// valid neighbor, already a member of the set).
__global__ __launch_bounds__(C_CH) void pool_mix_kernel(
    const float* __restrict__ fs,   // (N,128,1)
    const float* __restrict__ fv,   // (N,128,3)
    const float* __restrict__ Ws,
    const float* __restrict__ Wv,
    const float* __restrict__ bs,
    const float* __restrict__ bv,
    const int* __restrict__ nbr,
    const int* __restrict__ nsel,
    float* __restrict__ out_s,      // (M,128,1)
    float* __restrict__ out_v)      // (M,128,3)
{
  __shared__ float ps[C_CH];
  __shared__ float pv[C_CH*3];
  const int m = blockIdx.x, o = threadIdx.x;
  const int ns = nsel[m];
  float mS = -FLT_MAX, m0 = -FLT_MAX, m1 = -FLT_MAX, m2 = -FLT_MAX;
  for (int j = 0; j < ns; j++) {
    int n = nbr[m*K_LOC + j];
    mS = fmaxf(mS, fs[(size_t)n*C_CH + o]);
    const float* r = fv + (size_t)n*(C_CH*3) + 3*o;
    m0 = fmaxf(m0, r[0]); m1 = fmaxf(m1, r[1]); m2 = fmaxf(m2, r[2]);
  }
  ps[o] = mS; pv[3*o+0] = m0; pv[3*o+1] = m1; pv[3*o+2] = m2;
  __syncthreads();
  float aS = bs[o];
  float a0 = bv[o], a1 = bv[o], a2 = bv[o];
  for (int cc = 0; cc < C_CH; cc++) {
    float w1 = Ws[cc*C_CH + o];
    float w2 = Wv[cc*C_CH + o];
    aS = fmaf(ps[cc], w1, aS);
    a0 = fmaf(pv[3*cc+0], w2, a0);
    a1 = fmaf(pv[3*cc+1], w2, a1);
    a2 = fmaf(pv[3*cc+2], w2, a2);
  }
  out_s[(size_t)m*C_CH + o] = aS;
  float* ov = out_v + (size_t)m*(C_CH*3) + 3*o;
  ov[0] = a0; ov[1] = a1; ov[2] = a2;
}

extern "C" void kernel_launch(void* const* d_in, const int* in_sizes, int n_in,
                              void* d_out, int out_size, void* d_ws, size_t ws_size,
                              hipStream_t stream) {
  (void)in_sizes; (void)n_in; (void)out_size; (void)ws_size;
  const float* pos = (const float*)d_in[0];
  const float* fs  = (const float*)d_in[1];
  const float* fv  = (const float*)d_in[2];
  const float* Ws  = (const float*)d_in[3];
  const float* Wv  = (const float*)d_in[4];
  const float* bs  = (const float*)d_in[5];
  const float* bv  = (const float*)d_in[6];

  float* out      = (float*)d_out;
  float* cent_out = out;                               // 2048*3
  float* out_s    = out + 3*M_CENT;                    // 2048*128
  float* out_v    = out + 3*M_CENT + M_CENT*C_CH;      // 2048*128*3

  char* ws = (char*)d_ws;
  u64* slots = (u64*)ws;                                    // 1 MB (2048*64*8)
  int* nbr   = (int*)(ws + (size_t)M_CENT*64*8);            // 256 KB
  int* nsel  = (int*)(ws + (size_t)M_CENT*64*8 + M_CENT*K_LOC*4);

  init_ws_kernel<<<(M_CENT*64 + 255)/256, 256, 0, stream>>>(slots);
  fps_kernel<<<7, 512, 0, stream>>>(pos, slots, cent_out);
  ballq_kernel<<<M_CENT, BQ_NT, 0, stream>>>(pos, cent_out, nbr, nsel);
  pool_mix_kernel<<<M_CENT, C_CH, 0, stream>>>(fs, fv, Ws, Wv, bs, bv,
                                               nbr, nsel, out_s, out_v);
}